// Round 1
// baseline (8724.733 us; speedup 1.0000x reference)
//
#include <hip/hip_runtime.h>

// GCN: 3x (h = X@W; agg = scatter_add(norm_e * h[src] -> dst) + norm_self*h + b; relu)
// then mean-pool by graph id and a 128x8 linear head.
// All fp32. Edge aggregation via hardware f32 atomics into a zeroed buffer.

#define THREADS 256

// ---------------- degree / counts / rsqrt ----------------

__global__ __launch_bounds__(THREADS) void k_deg(const int* __restrict__ dst,
                                                 float* __restrict__ deg, int E) {
  int e = blockIdx.x * THREADS + threadIdx.x;
  if (e < E) atomicAdd(&deg[dst[e]], 1.0f);
}

__global__ __launch_bounds__(THREADS) void k_cnt(const int* __restrict__ batch,
                                                 float* __restrict__ cnts, int N) {
  int i = blockIdx.x * THREADS + threadIdx.x;
  if (i < N) atomicAdd(&cnts[batch[i]], 1.0f);
}

__global__ __launch_bounds__(THREADS) void k_rsq(float* __restrict__ deg, int N) {
  int i = blockIdx.x * THREADS + threadIdx.x;
  if (i < N) deg[i] = rsqrtf(deg[i] + 1.0f);  // deg -> dinv in place
}

// ---------------- GEMM: H[M,128] = X[M,128] @ W[128,128] ----------------
// Block: 256 threads, 64 rows. Thread (tx = t&31, ty = t>>5) computes
// rows r0+ty*8 .. +7, cols tx*4 .. +3 (8x4 micro-tile, 32 fp32 acc).
// W fully staged in LDS (64 KB -> 2 blocks/CU). X read as float4 broadcast
// loads (32 lanes share an address; block X footprint 32 KB, L1/L2-hit).

__global__ __launch_bounds__(THREADS) void k_gemm128(const float* __restrict__ X,
                                                     const float* __restrict__ W,
                                                     float* __restrict__ H, int M) {
  __shared__ float4 sW[128 * 32];  // [k][colgroup] : W[k][c0..c0+3]
  const int t = threadIdx.x;
#pragma unroll
  for (int i = 0; i < 16; ++i) sW[t + i * 256] = ((const float4*)W)[t + i * 256];
  __syncthreads();

  const int tx = t & 31;
  const int ty = t >> 5;
  const int r0 = blockIdx.x * 64 + ty * 8;

  const float* xp[8];
#pragma unroll
  for (int i = 0; i < 8; ++i) {
    int r = r0 + i;
    if (r >= M) r = M - 1;  // clamp for safe (discarded) loads
    xp[i] = X + (size_t)r * 128;
  }

  float4 acc[8];
#pragma unroll
  for (int i = 0; i < 8; ++i) acc[i] = make_float4(0.f, 0.f, 0.f, 0.f);

#pragma unroll 2
  for (int k = 0; k < 128; k += 4) {
    float4 xv[8];
#pragma unroll
    for (int i = 0; i < 8; ++i) xv[i] = *(const float4*)(xp[i] + k);
#pragma unroll
    for (int kk = 0; kk < 4; ++kk) {
      float4 w = sW[(k + kk) * 32 + tx];
#pragma unroll
      for (int i = 0; i < 8; ++i) {
        float xs = (kk == 0) ? xv[i].x : (kk == 1) ? xv[i].y : (kk == 2) ? xv[i].z : xv[i].w;
        acc[i].x = fmaf(xs, w.x, acc[i].x);
        acc[i].y = fmaf(xs, w.y, acc[i].y);
        acc[i].z = fmaf(xs, w.z, acc[i].z);
        acc[i].w = fmaf(xs, w.w, acc[i].w);
      }
    }
  }

#pragma unroll
  for (int i = 0; i < 8; ++i) {
    int r = r0 + i;
    if (r < M) *(float4*)(H + (size_t)r * 128 + tx * 4) = acc[i];
  }
}

// ---------------- edge scatter: AGG[dst] += norm_e * H[src] ----------------
// 32 lanes per edge, float4 per lane (512 B payload).

__global__ __launch_bounds__(THREADS) void k_scatter(const float* __restrict__ H,
                                                     const int* __restrict__ src,
                                                     const int* __restrict__ dst,
                                                     const float* __restrict__ dinv,
                                                     float* __restrict__ AGG, int E) {
  int gid = blockIdx.x * THREADS + threadIdx.x;
  int e = gid >> 5;
  int lane = gid & 31;
  if (e >= E) return;
  int s = src[e];
  int d = dst[e];
  float nrm = dinv[s] * dinv[d];
  float4 h = *(const float4*)(H + (size_t)s * 128 + lane * 4);
  float* o = AGG + (size_t)d * 128 + lane * 4;
  atomicAdd(o + 0, h.x * nrm);
  atomicAdd(o + 1, h.y * nrm);
  atomicAdd(o + 2, h.z * nrm);
  atomicAdd(o + 3, h.w * nrm);
}

// ---------------- finalize: B = B + A*dinv^2 + bias ; optional relu ----------------

__global__ __launch_bounds__(THREADS) void k_finalize(float* __restrict__ B,
                                                      const float* __restrict__ A,
                                                      const float* __restrict__ dinv,
                                                      const float* __restrict__ bias,
                                                      int N, int relu) {
  int gid = blockIdx.x * THREADS + threadIdx.x;
  int i = gid >> 5;
  int lane = gid & 31;
  if (i >= N) return;
  float di = dinv[i];
  float ns = di * di;
  float4 a = *(const float4*)(A + (size_t)i * 128 + lane * 4);
  float4 v = *(float4*)(B + (size_t)i * 128 + lane * 4);
  float4 bb = *(const float4*)(bias + lane * 4);
  v.x = fmaf(a.x, ns, v.x) + bb.x;
  v.y = fmaf(a.y, ns, v.y) + bb.y;
  v.z = fmaf(a.z, ns, v.z) + bb.z;
  v.w = fmaf(a.w, ns, v.w) + bb.w;
  if (relu) {
    v.x = fmaxf(v.x, 0.f);
    v.y = fmaxf(v.y, 0.f);
    v.z = fmaxf(v.z, 0.f);
    v.w = fmaxf(v.w, 0.f);
  }
  *(float4*)(B + (size_t)i * 128 + lane * 4) = v;
}

// ---------------- pooling: pooled[batch[i]] += H[i] ----------------

__global__ __launch_bounds__(THREADS) void k_pool(const float* __restrict__ H,
                                                  const int* __restrict__ batch,
                                                  float* __restrict__ pooled, int N) {
  int gid = blockIdx.x * THREADS + threadIdx.x;
  int i = gid >> 5;
  int lane = gid & 31;
  if (i >= N) return;
  int g = batch[i];
  float4 h = *(const float4*)(H + (size_t)i * 128 + lane * 4);
  float* o = pooled + (size_t)g * 128 + lane * 4;
  atomicAdd(o + 0, h.x);
  atomicAdd(o + 1, h.y);
  atomicAdd(o + 2, h.z);
  atomicAdd(o + 3, h.w);
}

// ---------------- head: out[g,o] = (pooled[g]/max(cnt,1)) . Wlin[:,o] + blin[o] ----------------

__global__ __launch_bounds__(THREADS) void k_head(const float* __restrict__ pooled,
                                                  const float* __restrict__ cnts,
                                                  const float* __restrict__ Wl,
                                                  const float* __restrict__ bl,
                                                  float* __restrict__ out, int G) {
  int gid = blockIdx.x * THREADS + threadIdx.x;
  int g = gid >> 3;
  int o = gid & 7;
  if (g >= G) return;
  float acc = 0.f;
#pragma unroll 8
  for (int k = 0; k < 128; ++k) acc = fmaf(pooled[(size_t)g * 128 + k], Wl[k * 8 + o], acc);
  out[g * 8 + o] = acc / fmaxf(cnts[g], 1.0f) + bl[o];
}

// ---------------- launch ----------------

extern "C" void kernel_launch(void* const* d_in, const int* in_sizes, int n_in,
                              void* d_out, int out_size, void* d_ws, size_t ws_size,
                              hipStream_t stream) {
  const float* x     = (const float*)d_in[0];
  const int*   ei    = (const int*)d_in[1];
  const int*   batch = (const int*)d_in[3];
  const float* W1 = (const float*)d_in[4];
  const float* b1 = (const float*)d_in[5];
  const float* W2 = (const float*)d_in[6];
  const float* b2 = (const float*)d_in[7];
  const float* W3 = (const float*)d_in[8];
  const float* b3 = (const float*)d_in[9];
  const float* Wl = (const float*)d_in[10];
  const float* bl = (const float*)d_in[11];
  float* out = (float*)d_out;

  const int N = in_sizes[0] / 128;
  const int E = in_sizes[1] / 2;
  const int G = out_size / 8;
  const int* srcp = ei;
  const int* dstp = ei + E;

  const size_t NB = (size_t)N * 128 * sizeof(float);
  char* ws = (char*)d_ws;
  float* A      = (float*)ws;             // h buffer
  float* B      = (float*)(ws + NB);      // agg / activation buffer
  float* deg    = (float*)(ws + 2 * NB);  // deg -> dinv
  float* pooled = deg + N;
  float* cnts   = pooled + (size_t)G * 128;

  // zero deg + pooled + cnts (contiguous)
  hipMemsetAsync(deg, 0, ((size_t)N + (size_t)G * 128 + (size_t)G) * sizeof(float), stream);

  int nbE = (E + THREADS - 1) / THREADS;
  int nbN = (N + THREADS - 1) / THREADS;
  k_deg<<<nbE, THREADS, 0, stream>>>(dstp, deg, E);
  k_cnt<<<nbN, THREADS, 0, stream>>>(batch, cnts, N);
  k_rsq<<<nbN, THREADS, 0, stream>>>(deg, N);

  int gemm_blocks = (N + 63) / 64;
  int sc_blocks = (int)(((long long)E * 32 + THREADS - 1) / THREADS);
  int fin_blocks = (int)(((long long)N * 32 + THREADS - 1) / THREADS);

  // ---- layer 1 ----
  k_gemm128<<<gemm_blocks, THREADS, 0, stream>>>(x, W1, A, N);
  hipMemsetAsync(B, 0, NB, stream);
  k_scatter<<<sc_blocks, THREADS, 0, stream>>>(A, srcp, dstp, deg, B, E);
  k_finalize<<<fin_blocks, THREADS, 0, stream>>>(B, A, deg, b1, N, 1);

  // ---- layer 2 ----
  k_gemm128<<<gemm_blocks, THREADS, 0, stream>>>(B, W2, A, N);
  hipMemsetAsync(B, 0, NB, stream);
  k_scatter<<<sc_blocks, THREADS, 0, stream>>>(A, srcp, dstp, deg, B, E);
  k_finalize<<<fin_blocks, THREADS, 0, stream>>>(B, A, deg, b2, N, 1);

  // ---- layer 3 (no relu) ----
  k_gemm128<<<gemm_blocks, THREADS, 0, stream>>>(B, W3, A, N);
  hipMemsetAsync(B, 0, NB, stream);
  k_scatter<<<sc_blocks, THREADS, 0, stream>>>(A, srcp, dstp, deg, B, E);
  k_finalize<<<fin_blocks, THREADS, 0, stream>>>(B, A, deg, b3, N, 0);

  // ---- pool + head ----
  k_pool<<<fin_blocks, THREADS, 0, stream>>>(B, batch, pooled, N);
  k_head<<<(G * 8 + THREADS - 1) / THREADS, THREADS, 0, stream>>>(pooled, cnts, Wl, bl, out, G);
}

// Round 2
// 1010.769 us; speedup vs baseline: 8.6318x; 8.6318x over previous
//
#include <hip/hip_runtime.h>

// GCN: 3x (h = X@W; agg = CSR-gather(norm_e * h[src]) + norm_self*h + b; relu)
// then mean-pool by graph id and a 128x8 linear head.
// R1: replaced atomic scatter (3.2 GB HBM write-through per layer) with a
// per-call dst-CSR build + register-accumulating gather (no f32 atomics).
// finalize + pooling fused into the gather.

#define THREADS 256

// ---------------- degree(int) / counts / dinv ----------------

__global__ __launch_bounds__(THREADS) void k_deg(const int* __restrict__ dst,
                                                 int* __restrict__ degi, int E) {
  int e = blockIdx.x * THREADS + threadIdx.x;
  if (e < E) atomicAdd(&degi[dst[e]], 1);
}

__global__ __launch_bounds__(THREADS) void k_cnt(const int* __restrict__ batch,
                                                 float* __restrict__ cnts, int N) {
  int i = blockIdx.x * THREADS + threadIdx.x;
  if (i < N) atomicAdd(&cnts[batch[i]], 1.0f);
}

__global__ __launch_bounds__(THREADS) void k_rsq(const int* __restrict__ degi,
                                                 float* __restrict__ dinv, int N) {
  int i = blockIdx.x * THREADS + threadIdx.x;
  if (i < N) dinv[i] = rsqrtf((float)degi[i] + 1.0f);
}

// ---------------- exclusive scan (3 kernels) ----------------

__global__ __launch_bounds__(THREADS) void k_scan1(const int* __restrict__ degi,
                                                   int* __restrict__ rowptr,
                                                   int* __restrict__ bsum, int N) {
  __shared__ int s[THREADS];
  int i = blockIdx.x * THREADS + threadIdx.x;
  int v = (i < N) ? degi[i] : 0;
  s[threadIdx.x] = v;
  __syncthreads();
#pragma unroll
  for (int off = 1; off < THREADS; off <<= 1) {
    int t = (threadIdx.x >= off) ? s[threadIdx.x - off] : 0;
    __syncthreads();
    s[threadIdx.x] += t;
    __syncthreads();
  }
  if (i < N) rowptr[i] = s[threadIdx.x] - v;  // exclusive
  if (threadIdx.x == THREADS - 1) bsum[blockIdx.x] = s[THREADS - 1];
}

__global__ __launch_bounds__(512) void k_scan2(int* __restrict__ bsum, int nb) {
  __shared__ int s[512];
  int v = (threadIdx.x < nb) ? bsum[threadIdx.x] : 0;
  s[threadIdx.x] = v;
  __syncthreads();
#pragma unroll
  for (int off = 1; off < 512; off <<= 1) {
    int t = (threadIdx.x >= off) ? s[threadIdx.x - off] : 0;
    __syncthreads();
    s[threadIdx.x] += t;
    __syncthreads();
  }
  if (threadIdx.x < nb) bsum[threadIdx.x] = s[threadIdx.x] - v;  // exclusive
}

__global__ __launch_bounds__(THREADS) void k_scan3(int* __restrict__ rowptr,
                                                   const int* __restrict__ bsum,
                                                   int N, int E) {
  int i = blockIdx.x * THREADS + threadIdx.x;
  if (i < N) rowptr[i] += bsum[blockIdx.x];
  if (i == 0) rowptr[N] = E;
}

// ---------------- CSR placement: csr_src/csr_w by dst ----------------

__global__ __launch_bounds__(THREADS) void k_csr(const int* __restrict__ src,
                                                 const int* __restrict__ dst,
                                                 const int* __restrict__ rowptr,
                                                 int* __restrict__ cursor,
                                                 const float* __restrict__ dinv,
                                                 int* __restrict__ csr_src,
                                                 float* __restrict__ csr_w, int E) {
  int e = blockIdx.x * THREADS + threadIdx.x;
  if (e >= E) return;
  int s = src[e];
  int d = dst[e];
  int pos = atomicAdd(&cursor[d], 1);
  int idx = rowptr[d] + pos;
  csr_src[idx] = s;
  csr_w[idx] = dinv[s] * dinv[d];
}

// ---------------- GEMM: H[M,128] = X[M,128] @ W[128,128] ----------------

__global__ __launch_bounds__(THREADS) void k_gemm128(const float* __restrict__ X,
                                                     const float* __restrict__ W,
                                                     float* __restrict__ H, int M) {
  __shared__ float4 sW[128 * 32];  // [k][colgroup] : W[k][c0..c0+3]
  const int t = threadIdx.x;
#pragma unroll
  for (int i = 0; i < 16; ++i) sW[t + i * 256] = ((const float4*)W)[t + i * 256];
  __syncthreads();

  const int tx = t & 31;
  const int ty = t >> 5;
  const int r0 = blockIdx.x * 64 + ty * 8;

  const float* xp[8];
#pragma unroll
  for (int i = 0; i < 8; ++i) {
    int r = r0 + i;
    if (r >= M) r = M - 1;
    xp[i] = X + (size_t)r * 128;
  }

  float4 acc[8];
#pragma unroll
  for (int i = 0; i < 8; ++i) acc[i] = make_float4(0.f, 0.f, 0.f, 0.f);

#pragma unroll 2
  for (int k = 0; k < 128; k += 4) {
    float4 xv[8];
#pragma unroll
    for (int i = 0; i < 8; ++i) xv[i] = *(const float4*)(xp[i] + k);
#pragma unroll
    for (int kk = 0; kk < 4; ++kk) {
      float4 w = sW[(k + kk) * 32 + tx];
#pragma unroll
      for (int i = 0; i < 8; ++i) {
        float xs = (kk == 0) ? xv[i].x : (kk == 1) ? xv[i].y : (kk == 2) ? xv[i].z : xv[i].w;
        acc[i].x = fmaf(xs, w.x, acc[i].x);
        acc[i].y = fmaf(xs, w.y, acc[i].y);
        acc[i].z = fmaf(xs, w.z, acc[i].z);
        acc[i].w = fmaf(xs, w.w, acc[i].w);
      }
    }
  }

#pragma unroll
  for (int i = 0; i < 8; ++i) {
    int r = r0 + i;
    if (r < M) *(float4*)(H + (size_t)r * 128 + tx * 4) = acc[i];
  }
}

// ---------------- gather: B[i] = sum_in csr_w*H[src] + dinv_i^2*H[i] + bias ----------------
// 32 lanes per dst node, float4 per lane. Optional relu; optional fused pool.

__global__ __launch_bounds__(THREADS) void k_gather(const float* __restrict__ H,
                                                    const int* __restrict__ rowptr,
                                                    const int* __restrict__ csr_src,
                                                    const float* __restrict__ csr_w,
                                                    const float* __restrict__ dinv,
                                                    const float* __restrict__ bias,
                                                    float* __restrict__ Bout, int N,
                                                    int relu,
                                                    const int* __restrict__ batch,
                                                    float* __restrict__ pooled) {
  int gid = blockIdx.x * THREADS + threadIdx.x;
  int i = gid >> 5;
  int lane = gid & 31;
  if (i >= N) return;
  int beg = rowptr[i];
  int end = rowptr[i + 1];

  float4 acc = make_float4(0.f, 0.f, 0.f, 0.f);
  int k = beg;
  for (; k + 1 < end; k += 2) {
    int s0 = csr_src[k], s1 = csr_src[k + 1];
    float w0 = csr_w[k], w1 = csr_w[k + 1];
    float4 h0 = *(const float4*)(H + (size_t)s0 * 128 + lane * 4);
    float4 h1 = *(const float4*)(H + (size_t)s1 * 128 + lane * 4);
    acc.x = fmaf(w0, h0.x, acc.x);
    acc.y = fmaf(w0, h0.y, acc.y);
    acc.z = fmaf(w0, h0.z, acc.z);
    acc.w = fmaf(w0, h0.w, acc.w);
    acc.x = fmaf(w1, h1.x, acc.x);
    acc.y = fmaf(w1, h1.y, acc.y);
    acc.z = fmaf(w1, h1.z, acc.z);
    acc.w = fmaf(w1, h1.w, acc.w);
  }
  if (k < end) {
    int s0 = csr_src[k];
    float w0 = csr_w[k];
    float4 h0 = *(const float4*)(H + (size_t)s0 * 128 + lane * 4);
    acc.x = fmaf(w0, h0.x, acc.x);
    acc.y = fmaf(w0, h0.y, acc.y);
    acc.z = fmaf(w0, h0.z, acc.z);
    acc.w = fmaf(w0, h0.w, acc.w);
  }

  float di = dinv[i];
  float ns = di * di;
  float4 hs = *(const float4*)(H + (size_t)i * 128 + lane * 4);
  float4 bb = *(const float4*)(bias + lane * 4);
  float4 v;
  v.x = fmaf(hs.x, ns, acc.x) + bb.x;
  v.y = fmaf(hs.y, ns, acc.y) + bb.y;
  v.z = fmaf(hs.z, ns, acc.z) + bb.z;
  v.w = fmaf(hs.w, ns, acc.w) + bb.w;
  if (relu) {
    v.x = fmaxf(v.x, 0.f);
    v.y = fmaxf(v.y, 0.f);
    v.z = fmaxf(v.z, 0.f);
    v.w = fmaxf(v.w, 0.f);
  }
  *(float4*)(Bout + (size_t)i * 128 + lane * 4) = v;

  if (pooled) {
    int g = batch[i];
    float* o = pooled + (size_t)g * 128 + lane * 4;
    atomicAdd(o + 0, v.x);
    atomicAdd(o + 1, v.y);
    atomicAdd(o + 2, v.z);
    atomicAdd(o + 3, v.w);
  }
}

// ---------------- head ----------------

__global__ __launch_bounds__(THREADS) void k_head(const float* __restrict__ pooled,
                                                  const float* __restrict__ cnts,
                                                  const float* __restrict__ Wl,
                                                  const float* __restrict__ bl,
                                                  float* __restrict__ out, int G) {
  int gid = blockIdx.x * THREADS + threadIdx.x;
  int g = gid >> 3;
  int o = gid & 7;
  if (g >= G) return;
  float acc = 0.f;
#pragma unroll 8
  for (int k = 0; k < 128; ++k) acc = fmaf(pooled[(size_t)g * 128 + k], Wl[k * 8 + o], acc);
  out[g * 8 + o] = acc / fmaxf(cnts[g], 1.0f) + bl[o];
}

// ---------------- launch ----------------

extern "C" void kernel_launch(void* const* d_in, const int* in_sizes, int n_in,
                              void* d_out, int out_size, void* d_ws, size_t ws_size,
                              hipStream_t stream) {
  const float* x     = (const float*)d_in[0];
  const int*   ei    = (const int*)d_in[1];
  const int*   batch = (const int*)d_in[3];
  const float* W1 = (const float*)d_in[4];
  const float* b1 = (const float*)d_in[5];
  const float* W2 = (const float*)d_in[6];
  const float* b2 = (const float*)d_in[7];
  const float* W3 = (const float*)d_in[8];
  const float* b3 = (const float*)d_in[9];
  const float* Wl = (const float*)d_in[10];
  const float* bl = (const float*)d_in[11];
  float* out = (float*)d_out;

  const int N = in_sizes[0] / 128;
  const int E = in_sizes[1] / 2;
  const int G = out_size / 8;
  const int* srcp = ei;
  const int* dstp = ei + E;

  char* ws = (char*)d_ws;
  float* A = (float*)ws;                       // [N,128] h buffer
  float* B = A + (size_t)N * 128;              // [N,128] agg/activation buffer
  // zeroed region: degi, cursor, cnts, pooled (contiguous)
  int*   degi   = (int*)(B + (size_t)N * 128); // N
  int*   cursor = degi + N;                    // N
  float* cnts   = (float*)(cursor + N);        // G
  float* pooled = cnts + G;                    // G*128
  // non-zeroed scratch
  float* dinv    = pooled + (size_t)G * 128;   // N
  int*   rowptr  = (int*)(dinv + N);           // N+1
  int*   bsum    = rowptr + N + 1;             // scan partials (<=2048)
  int*   csr_src = bsum + 2048;                // E
  float* csr_w   = (float*)(csr_src + E);      // E

  const size_t zero_bytes = ((size_t)2 * N + G + (size_t)G * 128) * sizeof(float);
  hipMemsetAsync(degi, 0, zero_bytes, stream);

  const int nbE = (E + THREADS - 1) / THREADS;
  const int nbN = (N + THREADS - 1) / THREADS;

  // ---- CSR build (once per call, reused by all 3 layers) ----
  k_deg<<<nbE, THREADS, 0, stream>>>(dstp, degi, E);
  k_cnt<<<nbN, THREADS, 0, stream>>>(batch, cnts, N);
  k_rsq<<<nbN, THREADS, 0, stream>>>(degi, dinv, N);
  k_scan1<<<nbN, THREADS, 0, stream>>>(degi, rowptr, bsum, N);
  k_scan2<<<1, 512, 0, stream>>>(bsum, nbN);
  k_scan3<<<nbN, THREADS, 0, stream>>>(rowptr, bsum, N, E);
  k_csr<<<nbE, THREADS, 0, stream>>>(srcp, dstp, rowptr, cursor, dinv, csr_src, csr_w, E);

  const int gemm_blocks = (N + 63) / 64;
  const int gat_blocks = (int)(((long long)N * 32 + THREADS - 1) / THREADS);

  // ---- layer 1 ----
  k_gemm128<<<gemm_blocks, THREADS, 0, stream>>>(x, W1, A, N);
  k_gather<<<gat_blocks, THREADS, 0, stream>>>(A, rowptr, csr_src, csr_w, dinv, b1, B, N, 1,
                                               nullptr, nullptr);
  // ---- layer 2 ----
  k_gemm128<<<gemm_blocks, THREADS, 0, stream>>>(B, W2, A, N);
  k_gather<<<gat_blocks, THREADS, 0, stream>>>(A, rowptr, csr_src, csr_w, dinv, b2, B, N, 1,
                                               nullptr, nullptr);
  // ---- layer 3 (no relu, fused mean-pool accumulation) ----
  k_gemm128<<<gemm_blocks, THREADS, 0, stream>>>(B, W3, A, N);
  k_gather<<<gat_blocks, THREADS, 0, stream>>>(A, rowptr, csr_src, csr_w, dinv, b3, B, N, 0,
                                               batch, pooled);

  // ---- head ----
  k_head<<<(G * 8 + THREADS - 1) / THREADS, THREADS, 0, stream>>>(pooled, cnts, Wl, bl, out, G);
}